// Round 10
// baseline (103.566 us; speedup 1.0000x reference)
//
#include <hip/hip_runtime.h>
#include <hip/hip_bf16.h>
#include <math.h>

#define BATCH  16384
#define XDIM   18
#define LATENT 16
#define NM     128
#define KDIM   4096
#define OUTF   64
#define KB     32
#define BM     64

typedef short s16x8 __attribute__((ext_vector_type(8)));
typedef float f32x16 __attribute__((ext_vector_type(16)));

__device__ __forceinline__ unsigned short f2bf(float f) {
    union { float f; unsigned u; } v; v.f = f;
    return (unsigned short)((v.u + 0x7FFFu + ((v.u >> 16) & 1u)) >> 16);
}
__device__ __forceinline__ unsigned pack_bf2(float a, float b) {
    __hip_bfloat162 h = __float22bfloat162_rn(make_float2(a, b));  // v_cvt_pk_bf16_f32
    return *(unsigned*)&h;
}
// swap bits 2 and 3 (the sigma' map: hacc C-row -> k index) — HW-verified r4-r9
__device__ __forceinline__ int swap23(int m) {
    return (m & ~12) | ((m & 4) << 1) | ((m & 8) >> 1);
}

// ---------------------------------------------------------------------------
// Precompute (unchanged, proven r4-r9): W_eff -> wfrag (B-frag layout),
// fc1_w -> f1frag (A-frag layout, sigma-permuted cols), fc1_b -> bh
// (hacc/C-layout, sigma-permuted), b_eff.
// wfrag:  [kc 0..255][ct 0..3][lane 0..63][8 bf16]
// f1frag: [jt 0..127][lane 0..63][8 bf16]
// ---------------------------------------------------------------------------
__global__ __launch_bounds__(128) void precompute_kernel(
    const float* __restrict__ x, const float* __restrict__ fc1_w,
    const float* __restrict__ fc1_b, const float* __restrict__ fc2_w,
    const float* __restrict__ fc2_b, const float* __restrict__ dil,
    const float* __restrict__ shf, unsigned short* __restrict__ wfrag,
    unsigned short* __restrict__ f1frag, float* __restrict__ bh,
    float* __restrict__ beff)
{
    const int tid = threadIdx.x;
    const int bid = blockIdx.x;
    if (bid < 512) {
        __shared__ float basis[KB];
        __shared__ float bred[32];
        if (tid < KB) {
            const float s   = x[(size_t)(BATCH - 1) * XDIM + 1];
            const float arg = s * dil[0] + shf[0];
            const float n   = 16.0f * (float)(tid & 15) / 15.0f;
            const float a   = arg * n;
            basis[tid] = (tid < 16) ? cosf(a) : sinf(a);
        }
        __syncthreads();
        const int m  = bid >> 2, kq = bid & 3;
        const int k8 = kq * 128 + tid;
        const int k  = k8 * 8;
        float acc[8] = {0.f,0.f,0.f,0.f,0.f,0.f,0.f,0.f};
        const float* src = fc2_w + (size_t)m * KB * KDIM + k;
        #pragma unroll 4
        for (int kb = 0; kb < KB; ++kb) {
            const float wgt = basis[kb];
            const float4 a = *(const float4*)(src + (size_t)kb * KDIM);
            const float4 b = *(const float4*)(src + (size_t)kb * KDIM + 4);
            acc[0] = fmaf(wgt, a.x, acc[0]); acc[1] = fmaf(wgt, a.y, acc[1]);
            acc[2] = fmaf(wgt, a.z, acc[2]); acc[3] = fmaf(wgt, a.w, acc[3]);
            acc[4] = fmaf(wgt, b.x, acc[4]); acc[5] = fmaf(wgt, b.y, acc[5]);
            acc[6] = fmaf(wgt, b.z, acc[6]); acc[7] = fmaf(wgt, b.w, acc[7]);
        }
        const int ct = m >> 5, coln = m & 31;
        const int kc = k8 >> 1, kg = k8 & 1;
        const int lane = kg * 32 + coln;
        unsigned short t[8];
        #pragma unroll
        for (int i = 0; i < 8; ++i) t[i] = f2bf(acc[i]);
        *(uint4*)(wfrag + ((size_t)(kc * 4 + ct) * 64 + lane) * 8) = *(const uint4*)t;
        if (kq == 0 && tid < 32) bred[tid] = basis[tid] * fc2_b[m * KB + tid];
        __syncthreads();
        if (kq == 0 && tid == 0) {
            float s = 0.f;
            #pragma unroll
            for (int i = 0; i < 32; ++i) s += bred[i];
            beff[m] = s;
        }
    } else if (bid < 576) {
        const int slot = (bid - 512) * 128 + tid;
        const int lane = slot & 63;
        const int jt   = slot >> 6;
        const int j    = jt * 32 + swap23(lane & 31);
        const int kg   = lane >> 5;
        const float* src = fc1_w + (size_t)j * LATENT + kg * 8;
        const float4 a = *(const float4*)(src);
        const float4 b = *(const float4*)(src + 4);
        unsigned short t[8];
        t[0]=f2bf(a.x); t[1]=f2bf(a.y); t[2]=f2bf(a.z); t[3]=f2bf(a.w);
        t[4]=f2bf(b.x); t[5]=f2bf(b.y); t[6]=f2bf(b.z); t[7]=f2bf(b.w);
        *(uint4*)(f1frag + (size_t)slot * 8) = *(const uint4*)t;
    } else {
        const int jt = tid;
        #pragma unroll
        for (int mp = 0; mp < 32; ++mp) {
            const int lg = mp >> 4, r = mp & 15;
            const int crow = (r & 3) + 8 * (r >> 2) + 4 * lg;
            bh[jt * 32 + mp] = fc1_b[jt * 32 + swap23(crow)];
        }
    }
}

// ---------------------------------------------------------------------------
// Fused (rt-fold + decoupled-hT): 256 blocks x 1024 thr (16 waves, 1 blk/CU).
// Wave = (ct = w&3, ks = w>>2): BOTH row halves (rt0/rt1), cols ct*32..+32,
// j-tiles ks*32..+32. Per iter t:
//   pack hc(t) for rt0/rt1 (computed previous iter -> latency covered)
//   hcA0/1 <- hT(t+1) MFMAs (overwrite after pack; one shared LDS bias read)
//   4 main MFMAs: each B-frag feeds both rt accs (B bytes halve vs r9)
//   prefetch B(t+2), fv(t+3)
// Tail: 4-pass sequential ks-reduce + epilogue.
// ---------------------------------------------------------------------------
__global__ __launch_bounds__(1024, 4) void fused_kernel(
    const float* __restrict__ x,
    const unsigned short* __restrict__ wfrag,
    const unsigned short* __restrict__ f1frag,
    const float* __restrict__ bh,
    const float* __restrict__ beff, float* __restrict__ out)
{
    __shared__ float bhs[132 * 32];    // bias (hacc layout) + zeroed overrun pad
    __shared__ float wfull[BM * NM];   // 32 KB

    const int tid = threadIdx.x;
    const int w   = tid >> 6, l = tid & 63;
    const int l31 = l & 31,  lg = l >> 5;
    const int row0 = blockIdx.x * BM;
    const int ct = w & 3, ks = w >> 2;

    // stage bias table + zero the 4-row overrun pad
    ((float4*)bhs)[tid] = ((const float4*)bh)[tid];
    if (tid < 32) ((float4*)bhs)[1024 + tid] = make_float4(0.f, 0.f, 0.f, 0.f);

    // zfrag0/1: lane l holds z[row0 + rt*32 + l31][lg*8 + r]  (loop-invariant)
    s16x8 zfrag0, zfrag1;
    {
        const float* zp0 = x + (size_t)(row0 + l31) * XDIM + 2 + lg * 8;
        const float* zp1 = x + (size_t)(row0 + 32 + l31) * XDIM + 2 + lg * 8;
        #pragma unroll
        for (int q = 0; q < 4; ++q) {
            const float2 t0 = *(const float2*)(zp0 + 2 * q);
            const float2 t1 = *(const float2*)(zp1 + 2 * q);
            ((unsigned*)&zfrag0)[q] = pack_bf2(t0.x, t0.y);
            ((unsigned*)&zfrag1)[q] = pack_bf2(t1.x, t1.y);
        }
    }

    f32x16 acc0, acc1;
    #pragma unroll
    for (int i = 0; i < 16; ++i) { acc0[i] = 0.0f; acc1[i] = 0.0f; }

    // pointers: fv(i) at fvp + i*512; B(i) at bp + i*4096 (kc1 at +2048)
    const unsigned short* fvp = f1frag + ((size_t)(ks * 32) * 64 + l) * 8;
    const unsigned short* bp  = wfrag + ((size_t)(2 * (ks * 32)) * 4 + ct) * 512 + l * 8;

    // prologue global loads
    const uint4 fv0 = *(const uint4*)(fvp);
    uint4 fvA = *(const uint4*)(fvp + 512);    // fv(1) -> hT in even body
    uint4 fvB = *(const uint4*)(fvp + 1024);   // fv(2) -> hT in odd body
    s16x8 B0E = *(const s16x8*)(bp);
    s16x8 B1E = *(const s16x8*)(bp + 2048);
    s16x8 B0O = *(const s16x8*)(bp + 4096);
    s16x8 B1O = *(const s16x8*)(bp + 4096 + 2048);

    __syncthreads();   // bhs ready
    const float* bhp = bhs + (ks * 32) * 32 + lg * 16;

    auto hinit = [&](const float* bq) -> f32x16 {
        const float4 c0 = *(const float4*)(bq);
        const float4 c1 = *(const float4*)(bq + 4);
        const float4 c2 = *(const float4*)(bq + 8);
        const float4 c3 = *(const float4*)(bq + 12);
        f32x16 hc;
        hc[0]=c0.x;  hc[1]=c0.y;  hc[2]=c0.z;  hc[3]=c0.w;
        hc[4]=c1.x;  hc[5]=c1.y;  hc[6]=c1.z;  hc[7]=c1.w;
        hc[8]=c2.x;  hc[9]=c2.y;  hc[10]=c2.z; hc[11]=c2.w;
        hc[12]=c3.x; hc[13]=c3.y; hc[14]=c3.z; hc[15]=c3.w;
        return hc;
    };

    // hc(0) for both row halves
    f32x16 hi0 = hinit(bhp);
    f32x16 hcA0 = __builtin_amdgcn_mfma_f32_32x32x16_bf16(*(const s16x8*)&fv0, zfrag0, hi0, 0, 0, 0);
    f32x16 hcA1 = __builtin_amdgcn_mfma_f32_32x32x16_bf16(*(const s16x8*)&fv0, zfrag1, hi0, 0, 0, 0);

    for (int t = 0; t < 32; t += 2) {
        // ---- even iter t ----
        {
            unsigned p00[4], p01[4], p10[4], p11[4];
            #pragma unroll
            for (int q = 0; q < 4; ++q) {
                p00[q] = pack_bf2(fmaxf(hcA0[2*q],   0.f), fmaxf(hcA0[2*q+1],   0.f));
                p01[q] = pack_bf2(fmaxf(hcA0[8+2*q], 0.f), fmaxf(hcA0[8+2*q+1], 0.f));
                p10[q] = pack_bf2(fmaxf(hcA1[2*q],   0.f), fmaxf(hcA1[2*q+1],   0.f));
                p11[q] = pack_bf2(fmaxf(hcA1[8+2*q], 0.f), fmaxf(hcA1[8+2*q+1], 0.f));
            }
            // hT(t+1): overwrite hcA (WAR after pack), shared bias read
            f32x16 hi = hinit(bhp + 32);
            hcA0 = __builtin_amdgcn_mfma_f32_32x32x16_bf16(*(const s16x8*)&fvA, zfrag0, hi, 0, 0, 0);
            hcA1 = __builtin_amdgcn_mfma_f32_32x32x16_bf16(*(const s16x8*)&fvA, zfrag1, hi, 0, 0, 0);
            fvA = *(const uint4*)(fvp + 1536);   // fv(t+3)
            // 4 mains: each B feeds both rt accs
            acc0 = __builtin_amdgcn_mfma_f32_32x32x16_bf16(*(const s16x8*)p00, B0E, acc0, 0, 0, 0);
            acc1 = __builtin_amdgcn_mfma_f32_32x32x16_bf16(*(const s16x8*)p10, B0E, acc1, 0, 0, 0);
            acc0 = __builtin_amdgcn_mfma_f32_32x32x16_bf16(*(const s16x8*)p01, B1E, acc0, 0, 0, 0);
            acc1 = __builtin_amdgcn_mfma_f32_32x32x16_bf16(*(const s16x8*)p11, B1E, acc1, 0, 0, 0);
            B0E = *(const s16x8*)(bp + 8192);            // B(t+2)
            B1E = *(const s16x8*)(bp + 8192 + 2048);
        }
        // ---- odd iter t+1 ----
        {
            unsigned p00[4], p01[4], p10[4], p11[4];
            #pragma unroll
            for (int q = 0; q < 4; ++q) {
                p00[q] = pack_bf2(fmaxf(hcA0[2*q],   0.f), fmaxf(hcA0[2*q+1],   0.f));
                p01[q] = pack_bf2(fmaxf(hcA0[8+2*q], 0.f), fmaxf(hcA0[8+2*q+1], 0.f));
                p10[q] = pack_bf2(fmaxf(hcA1[2*q],   0.f), fmaxf(hcA1[2*q+1],   0.f));
                p11[q] = pack_bf2(fmaxf(hcA1[8+2*q], 0.f), fmaxf(hcA1[8+2*q+1], 0.f));
            }
            f32x16 hi = hinit(bhp + 64);
            hcA0 = __builtin_amdgcn_mfma_f32_32x32x16_bf16(*(const s16x8*)&fvB, zfrag0, hi, 0, 0, 0);
            hcA1 = __builtin_amdgcn_mfma_f32_32x32x16_bf16(*(const s16x8*)&fvB, zfrag1, hi, 0, 0, 0);
            fvB = *(const uint4*)(fvp + 2048);   // fv(t+4)
            acc0 = __builtin_amdgcn_mfma_f32_32x32x16_bf16(*(const s16x8*)p00, B0O, acc0, 0, 0, 0);
            acc1 = __builtin_amdgcn_mfma_f32_32x32x16_bf16(*(const s16x8*)p10, B0O, acc1, 0, 0, 0);
            acc0 = __builtin_amdgcn_mfma_f32_32x32x16_bf16(*(const s16x8*)p01, B1O, acc0, 0, 0, 0);
            acc1 = __builtin_amdgcn_mfma_f32_32x32x16_bf16(*(const s16x8*)p11, B1O, acc1, 0, 0, 0);
            B0O = *(const s16x8*)(bp + 12288);           // B(t+3)
            B1O = *(const s16x8*)(bp + 12288 + 2048);
        }
        fvp += 1024; bp += 8192; bhp += 64;
    }

    // deterministic sequential ks-reduce through LDS + b_eff (4 passes)
    #pragma unroll 1
    for (int p = 0; p < 4; ++p) {
        if (ks == p) {
            const float be = beff[ct * 32 + l31];
            #pragma unroll
            for (int r = 0; r < 16; ++r) {
                const int rowl = (r & 3) + 8 * (r >> 2) + 4 * lg;
                const int idx  = rowl * NM + ct * 32 + l31;
                if (p == 0) {
                    wfull[idx]             = acc0[r] + be;
                    wfull[idx + 32 * NM]   = acc1[r] + be;
                } else {
                    wfull[idx]           += acc0[r];
                    wfull[idx + 32 * NM] += acc1[r];
                }
            }
        }
        __syncthreads();
    }

    // out[b,o] = inp[b] * w[b,o] + w[b,64+o]
    {
        const int o = tid & 63, rg = tid >> 6;
        #pragma unroll
        for (int i = 0; i < 4; ++i) {
            const int r = rg * 4 + i;
            const float inp = x[(size_t)(row0 + r) * XDIM];
            out[(size_t)(row0 + r) * OUTF + o] =
                fmaf(inp, wfull[r * NM + o], wfull[r * NM + OUTF + o]);
        }
    }
}

// ---------------------------------------------------------------------------
extern "C" void kernel_launch(void* const* d_in, const int* in_sizes, int n_in,
                              void* d_out, int out_size, void* d_ws, size_t ws_size,
                              hipStream_t stream) {
    const float* x     = (const float*)d_in[0];
    const float* fc1_w = (const float*)d_in[1];
    const float* fc1_b = (const float*)d_in[2];
    const float* fc2_w = (const float*)d_in[3];
    const float* fc2_b = (const float*)d_in[4];
    const float* dil   = (const float*)d_in[5];
    const float* shf   = (const float*)d_in[6];
    float* out = (float*)d_out;

    // ws: wfrag 1 MB | f1frag 128 KB | beff 512 B | bh 16 KB
    unsigned short* wfrag  = (unsigned short*)d_ws;
    unsigned short* f1frag = wfrag + 524288;
    float*          beff   = (float*)(f1frag + 65536);
    float*          bh     = beff + NM;

    precompute_kernel<<<577, 128, 0, stream>>>(x, fc1_w, fc1_b, fc2_w, fc2_b,
                                               dil, shf, wfrag, f1frag, bh, beff);
    fused_kernel<<<BATCH / BM, 1024, 0, stream>>>(x, wfrag, f1frag, bh, beff, out);
}

// Round 11
// 61.005 us; speedup vs baseline: 1.6977x; 1.6977x over previous
//
#include <hip/hip_runtime.h>
#include <hip/hip_bf16.h>
#include <math.h>

#define BATCH  16384
#define XDIM   18
#define LATENT 16
#define NM     128
#define KDIM   4096
#define OUTF   64
#define KB     32
#define BM     64

typedef short s16x8 __attribute__((ext_vector_type(8)));
typedef float f32x16 __attribute__((ext_vector_type(16)));

__device__ __forceinline__ unsigned short f2bf(float f) {
    union { float f; unsigned u; } v; v.f = f;
    return (unsigned short)((v.u + 0x7FFFu + ((v.u >> 16) & 1u)) >> 16);
}
__device__ __forceinline__ unsigned pack_bf2(float a, float b) {
    __hip_bfloat162 h = __float22bfloat162_rn(make_float2(a, b));  // v_cvt_pk_bf16_f32
    return *(unsigned*)&h;
}
// swap bits 2 and 3 (the sigma' map: hacc C-row -> k index) — HW-verified r4-r10
__device__ __forceinline__ int swap23(int m) {
    return (m & ~12) | ((m & 4) << 1) | ((m & 8) >> 1);
}

// ---------------------------------------------------------------------------
// Precompute (unchanged, proven r4-r10): W_eff -> wfrag (B-frag layout),
// fc1_w -> f1frag (A-frag layout, sigma-permuted cols), fc1_b -> bh
// (hacc/C-layout, sigma-permuted), b_eff.
// wfrag:  [kc 0..255][ct 0..3][lane 0..63][8 bf16]
// f1frag: [jt 0..127][lane 0..63][8 bf16]
// ---------------------------------------------------------------------------
__global__ __launch_bounds__(128) void precompute_kernel(
    const float* __restrict__ x, const float* __restrict__ fc1_w,
    const float* __restrict__ fc1_b, const float* __restrict__ fc2_w,
    const float* __restrict__ fc2_b, const float* __restrict__ dil,
    const float* __restrict__ shf, unsigned short* __restrict__ wfrag,
    unsigned short* __restrict__ f1frag, float* __restrict__ bh,
    float* __restrict__ beff)
{
    const int tid = threadIdx.x;
    const int bid = blockIdx.x;
    if (bid < 512) {
        __shared__ float basis[KB];
        __shared__ float bred[32];
        if (tid < KB) {
            const float s   = x[(size_t)(BATCH - 1) * XDIM + 1];
            const float arg = s * dil[0] + shf[0];
            const float n   = 16.0f * (float)(tid & 15) / 15.0f;
            const float a   = arg * n;
            basis[tid] = (tid < 16) ? cosf(a) : sinf(a);
        }
        __syncthreads();
        const int m  = bid >> 2, kq = bid & 3;
        const int k8 = kq * 128 + tid;
        const int k  = k8 * 8;
        float acc[8] = {0.f,0.f,0.f,0.f,0.f,0.f,0.f,0.f};
        const float* src = fc2_w + (size_t)m * KB * KDIM + k;
        #pragma unroll 4
        for (int kb = 0; kb < KB; ++kb) {
            const float wgt = basis[kb];
            const float4 a = *(const float4*)(src + (size_t)kb * KDIM);
            const float4 b = *(const float4*)(src + (size_t)kb * KDIM + 4);
            acc[0] = fmaf(wgt, a.x, acc[0]); acc[1] = fmaf(wgt, a.y, acc[1]);
            acc[2] = fmaf(wgt, a.z, acc[2]); acc[3] = fmaf(wgt, a.w, acc[3]);
            acc[4] = fmaf(wgt, b.x, acc[4]); acc[5] = fmaf(wgt, b.y, acc[5]);
            acc[6] = fmaf(wgt, b.z, acc[6]); acc[7] = fmaf(wgt, b.w, acc[7]);
        }
        const int ct = m >> 5, coln = m & 31;
        const int kc = k8 >> 1, kg = k8 & 1;
        const int lane = kg * 32 + coln;
        unsigned short t[8];
        #pragma unroll
        for (int i = 0; i < 8; ++i) t[i] = f2bf(acc[i]);
        *(uint4*)(wfrag + ((size_t)(kc * 4 + ct) * 64 + lane) * 8) = *(const uint4*)t;
        if (kq == 0 && tid < 32) bred[tid] = basis[tid] * fc2_b[m * KB + tid];
        __syncthreads();
        if (kq == 0 && tid == 0) {
            float s = 0.f;
            #pragma unroll
            for (int i = 0; i < 32; ++i) s += bred[i];
            beff[m] = s;
        }
    } else if (bid < 576) {
        const int slot = (bid - 512) * 128 + tid;
        const int lane = slot & 63;
        const int jt   = slot >> 6;
        const int j    = jt * 32 + swap23(lane & 31);
        const int kg   = lane >> 5;
        const float* src = fc1_w + (size_t)j * LATENT + kg * 8;
        const float4 a = *(const float4*)(src);
        const float4 b = *(const float4*)(src + 4);
        unsigned short t[8];
        t[0]=f2bf(a.x); t[1]=f2bf(a.y); t[2]=f2bf(a.z); t[3]=f2bf(a.w);
        t[4]=f2bf(b.x); t[5]=f2bf(b.y); t[6]=f2bf(b.z); t[7]=f2bf(b.w);
        *(uint4*)(f1frag + (size_t)slot * 8) = *(const uint4*)t;
    } else {
        const int jt = tid;
        #pragma unroll
        for (int mp = 0; mp < 32; ++mp) {
            const int lg = mp >> 4, r = mp & 15;
            const int crow = (r & 3) + 8 * (r >> 2) + 4 * lg;
            bh[jt * 32 + mp] = fc1_b[jt * 32 + swap23(crow)];
        }
    }
}

// ---------------------------------------------------------------------------
// Fused (rt-fold, register-frugal): 256 blocks x 1024 thr (16 waves, 1/CU).
// Wave = (ct = w&3, ks = w>>2): BOTH row halves, cols ct*32..+32, j-tiles
// ks*32..+32. Per body t (serialized rt phases to cap live registers):
//   pack hcA0(t) -> 2 mains into acc0 ; hcA0 <- hT(t+1,rt0)  [hi shared]
//   pack hcA1(t) -> 2 mains into acc1 ; hcA1 <- hT(t+1,rt1)
//   prefetch B(t+2), fv(t+3)   [distance-2, static sets E/O]
// Budget: acc 32 + hc 32 + z 8 + B 16 + fv 8 + hi 16 + pack 8 ~ 126 <= 128
// (4 waves/SIMD). Tail: 4-pass sequential ks-reduce + epilogue.
// ---------------------------------------------------------------------------
__global__ __launch_bounds__(1024, 4) void fused_kernel(
    const float* __restrict__ x,
    const unsigned short* __restrict__ wfrag,
    const unsigned short* __restrict__ f1frag,
    const float* __restrict__ bh,
    const float* __restrict__ beff, float* __restrict__ out)
{
    __shared__ float bhs[132 * 32];    // bias (hacc layout) + zeroed overrun pad
    __shared__ float wfull[BM * NM];   // 32 KB

    const int tid = threadIdx.x;
    const int w   = tid >> 6, l = tid & 63;
    const int l31 = l & 31,  lg = l >> 5;
    const int row0 = blockIdx.x * BM;
    const int ct = w & 3, ks = w >> 2;

    // stage bias table + zero the 4-row overrun pad
    ((float4*)bhs)[tid] = ((const float4*)bh)[tid];
    if (tid < 32) ((float4*)bhs)[1024 + tid] = make_float4(0.f, 0.f, 0.f, 0.f);

    // zfrag0/1: lane l holds z[row0 + rt*32 + l31][lg*8 + r]  (loop-invariant)
    s16x8 zfrag0, zfrag1;
    {
        const float* zp0 = x + (size_t)(row0 + l31) * XDIM + 2 + lg * 8;
        const float* zp1 = x + (size_t)(row0 + 32 + l31) * XDIM + 2 + lg * 8;
        #pragma unroll
        for (int q = 0; q < 4; ++q) {
            const float2 t0 = *(const float2*)(zp0 + 2 * q);
            const float2 t1 = *(const float2*)(zp1 + 2 * q);
            ((unsigned*)&zfrag0)[q] = pack_bf2(t0.x, t0.y);
            ((unsigned*)&zfrag1)[q] = pack_bf2(t1.x, t1.y);
        }
    }

    f32x16 acc0, acc1;
    #pragma unroll
    for (int i = 0; i < 16; ++i) { acc0[i] = 0.0f; acc1[i] = 0.0f; }

    // pointers: fv(i) at fvp + i*512; B(i) at bp + i*4096 (kc1 at +2048)
    const unsigned short* fvp = f1frag + ((size_t)(ks * 32) * 64 + l) * 8;
    const unsigned short* bp  = wfrag + ((size_t)(2 * (ks * 32)) * 4 + ct) * 512 + l * 8;

    // prologue global loads
    const uint4 fv0 = *(const uint4*)(fvp);
    uint4 fvA = *(const uint4*)(fvp + 512);    // fv(t+1) for even bodies
    uint4 fvB = *(const uint4*)(fvp + 1024);   // fv(t+2) for odd bodies
    s16x8 B0E = *(const s16x8*)(bp);
    s16x8 B1E = *(const s16x8*)(bp + 2048);
    s16x8 B0O = *(const s16x8*)(bp + 4096);
    s16x8 B1O = *(const s16x8*)(bp + 4096 + 2048);

    __syncthreads();   // bhs ready
    const float* bhp = bhs + (ks * 32) * 32 + lg * 16;

    auto hinit = [&](const float* bq) -> f32x16 {
        const float4 c0 = *(const float4*)(bq);
        const float4 c1 = *(const float4*)(bq + 4);
        const float4 c2 = *(const float4*)(bq + 8);
        const float4 c3 = *(const float4*)(bq + 12);
        f32x16 hc;
        hc[0]=c0.x;  hc[1]=c0.y;  hc[2]=c0.z;  hc[3]=c0.w;
        hc[4]=c1.x;  hc[5]=c1.y;  hc[6]=c1.z;  hc[7]=c1.w;
        hc[8]=c2.x;  hc[9]=c2.y;  hc[10]=c2.z; hc[11]=c2.w;
        hc[12]=c3.x; hc[13]=c3.y; hc[14]=c3.z; hc[15]=c3.w;
        return hc;
    };

    // hc(0) for both row halves
    {
        f32x16 hi0 = hinit(bhp);
        // declared below; initialize here
    }
    f32x16 hcA0, hcA1;
    {
        f32x16 hi0 = hinit(bhp);
        hcA0 = __builtin_amdgcn_mfma_f32_32x32x16_bf16(*(const s16x8*)&fv0, zfrag0, hi0, 0, 0, 0);
        hcA1 = __builtin_amdgcn_mfma_f32_32x32x16_bf16(*(const s16x8*)&fv0, zfrag1, hi0, 0, 0, 0);
    }

    #pragma unroll 1
    for (int t = 0; t < 32; t += 2) {
        // ---- even body t: consume E set ----
        {
            // rt0: pack hc(t), 2 mains, then overwrite hcA0 with hT(t+1)
            {
                unsigned p0[4], p1[4];
                #pragma unroll
                for (int q = 0; q < 4; ++q) {
                    p0[q] = pack_bf2(fmaxf(hcA0[2*q],   0.f), fmaxf(hcA0[2*q+1],   0.f));
                    p1[q] = pack_bf2(fmaxf(hcA0[8+2*q], 0.f), fmaxf(hcA0[8+2*q+1], 0.f));
                }
                acc0 = __builtin_amdgcn_mfma_f32_32x32x16_bf16(*(const s16x8*)p0, B0E, acc0, 0, 0, 0);
                acc0 = __builtin_amdgcn_mfma_f32_32x32x16_bf16(*(const s16x8*)p1, B1E, acc0, 0, 0, 0);
            }
            f32x16 hi = hinit(bhp + 32);
            hcA0 = __builtin_amdgcn_mfma_f32_32x32x16_bf16(*(const s16x8*)&fvA, zfrag0, hi, 0, 0, 0);
            // rt1: pack hc(t), 2 mains, then overwrite hcA1 with hT(t+1)
            {
                unsigned q0[4], q1[4];
                #pragma unroll
                for (int q = 0; q < 4; ++q) {
                    q0[q] = pack_bf2(fmaxf(hcA1[2*q],   0.f), fmaxf(hcA1[2*q+1],   0.f));
                    q1[q] = pack_bf2(fmaxf(hcA1[8+2*q], 0.f), fmaxf(hcA1[8+2*q+1], 0.f));
                }
                acc1 = __builtin_amdgcn_mfma_f32_32x32x16_bf16(*(const s16x8*)q0, B0E, acc1, 0, 0, 0);
                acc1 = __builtin_amdgcn_mfma_f32_32x32x16_bf16(*(const s16x8*)q1, B1E, acc1, 0, 0, 0);
            }
            hcA1 = __builtin_amdgcn_mfma_f32_32x32x16_bf16(*(const s16x8*)&fvA, zfrag1, hi, 0, 0, 0);
            fvA = *(const uint4*)(fvp + 1536);           // fv(t+3)
            B0E = *(const s16x8*)(bp + 8192);            // B(t+2)
            B1E = *(const s16x8*)(bp + 8192 + 2048);
        }
        // ---- odd body t+1: consume O set ----
        {
            {
                unsigned p0[4], p1[4];
                #pragma unroll
                for (int q = 0; q < 4; ++q) {
                    p0[q] = pack_bf2(fmaxf(hcA0[2*q],   0.f), fmaxf(hcA0[2*q+1],   0.f));
                    p1[q] = pack_bf2(fmaxf(hcA0[8+2*q], 0.f), fmaxf(hcA0[8+2*q+1], 0.f));
                }
                acc0 = __builtin_amdgcn_mfma_f32_32x32x16_bf16(*(const s16x8*)p0, B0O, acc0, 0, 0, 0);
                acc0 = __builtin_amdgcn_mfma_f32_32x32x16_bf16(*(const s16x8*)p1, B1O, acc0, 0, 0, 0);
            }
            f32x16 hi = hinit(bhp + 64);
            hcA0 = __builtin_amdgcn_mfma_f32_32x32x16_bf16(*(const s16x8*)&fvB, zfrag0, hi, 0, 0, 0);
            {
                unsigned q0[4], q1[4];
                #pragma unroll
                for (int q = 0; q < 4; ++q) {
                    q0[q] = pack_bf2(fmaxf(hcA1[2*q],   0.f), fmaxf(hcA1[2*q+1],   0.f));
                    q1[q] = pack_bf2(fmaxf(hcA1[8+2*q], 0.f), fmaxf(hcA1[8+2*q+1], 0.f));
                }
                acc1 = __builtin_amdgcn_mfma_f32_32x32x16_bf16(*(const s16x8*)q0, B0O, acc1, 0, 0, 0);
                acc1 = __builtin_amdgcn_mfma_f32_32x32x16_bf16(*(const s16x8*)q1, B1O, acc1, 0, 0, 0);
            }
            hcA1 = __builtin_amdgcn_mfma_f32_32x32x16_bf16(*(const s16x8*)&fvB, zfrag1, hi, 0, 0, 0);
            fvB = *(const uint4*)(fvp + 2048);           // fv(t+4)
            B0O = *(const s16x8*)(bp + 12288);           // B(t+3)
            B1O = *(const s16x8*)(bp + 12288 + 2048);
        }
        fvp += 1024; bp += 8192; bhp += 64;
    }

    // deterministic sequential ks-reduce through LDS + b_eff (4 passes)
    #pragma unroll 1
    for (int p = 0; p < 4; ++p) {
        if (ks == p) {
            const float be = beff[ct * 32 + l31];
            #pragma unroll
            for (int r = 0; r < 16; ++r) {
                const int rowl = (r & 3) + 8 * (r >> 2) + 4 * lg;
                const int idx  = rowl * NM + ct * 32 + l31;
                if (p == 0) {
                    wfull[idx]             = acc0[r] + be;
                    wfull[idx + 32 * NM]   = acc1[r] + be;
                } else {
                    wfull[idx]           += acc0[r];
                    wfull[idx + 32 * NM] += acc1[r];
                }
            }
        }
        __syncthreads();
    }

    // out[b,o] = inp[b] * w[b,o] + w[b,64+o]
    {
        const int o = tid & 63, rg = tid >> 6;
        #pragma unroll
        for (int i = 0; i < 4; ++i) {
            const int r = rg * 4 + i;
            const float inp = x[(size_t)(row0 + r) * XDIM];
            out[(size_t)(row0 + r) * OUTF + o] =
                fmaf(inp, wfull[r * NM + o], wfull[r * NM + OUTF + o]);
        }
    }
}

// ---------------------------------------------------------------------------
extern "C" void kernel_launch(void* const* d_in, const int* in_sizes, int n_in,
                              void* d_out, int out_size, void* d_ws, size_t ws_size,
                              hipStream_t stream) {
    const float* x     = (const float*)d_in[0];
    const float* fc1_w = (const float*)d_in[1];
    const float* fc1_b = (const float*)d_in[2];
    const float* fc2_w = (const float*)d_in[3];
    const float* fc2_b = (const float*)d_in[4];
    const float* dil   = (const float*)d_in[5];
    const float* shf   = (const float*)d_in[6];
    float* out = (float*)d_out;

    // ws: wfrag 1 MB | f1frag 128 KB | beff 512 B | bh 16 KB
    unsigned short* wfrag  = (unsigned short*)d_ws;
    unsigned short* f1frag = wfrag + 524288;
    float*          beff   = (float*)(f1frag + 65536);
    float*          bh     = beff + NM;

    precompute_kernel<<<577, 128, 0, stream>>>(x, fc1_w, fc1_b, fc2_w, fc2_b,
                                               dil, shf, wfrag, f1frag, bh, beff);
    fused_kernel<<<BATCH / BM, 1024, 0, stream>>>(x, wfrag, f1frag, bh, beff, out);
}

// Round 12
// 49.116 us; speedup vs baseline: 2.1086x; 1.2421x over previous
//
#include <hip/hip_runtime.h>
#include <hip/hip_bf16.h>
#include <math.h>

#define BATCH  16384
#define XDIM   18
#define LATENT 16
#define NM     128
#define KDIM   4096
#define OUTF   64
#define KB     32
#define BM     64

#define LDS_BYTES 147968   // ring 128 KB + bhs 16.9 KB (wfull aliases ring)

typedef short s16x8 __attribute__((ext_vector_type(8)));
typedef float f32x16 __attribute__((ext_vector_type(16)));

__device__ __forceinline__ unsigned short f2bf(float f) {
    union { float f; unsigned u; } v; v.f = f;
    return (unsigned short)((v.u + 0x7FFFu + ((v.u >> 16) & 1u)) >> 16);
}
__device__ __forceinline__ unsigned pack_bf2(float a, float b) {
    __hip_bfloat162 h = __float22bfloat162_rn(make_float2(a, b));  // v_cvt_pk_bf16_f32
    return *(unsigned*)&h;
}
// swap bits 2 and 3 (the sigma' map: hacc C-row -> k index) — HW-verified r4-r11
__device__ __forceinline__ int swap23(int m) {
    return (m & ~12) | ((m & 4) << 1) | ((m & 8) >> 1);
}

// ---------------------------------------------------------------------------
// Precompute (unchanged, proven r4-r11).
// wfrag:  [kc 0..255][ct 0..3][lane 0..63][8 bf16]
// f1frag: [jt 0..127][lane 0..63][8 bf16]
// ---------------------------------------------------------------------------
__global__ __launch_bounds__(128) void precompute_kernel(
    const float* __restrict__ x, const float* __restrict__ fc1_w,
    const float* __restrict__ fc1_b, const float* __restrict__ fc2_w,
    const float* __restrict__ fc2_b, const float* __restrict__ dil,
    const float* __restrict__ shf, unsigned short* __restrict__ wfrag,
    unsigned short* __restrict__ f1frag, float* __restrict__ bh,
    float* __restrict__ beff)
{
    const int tid = threadIdx.x;
    const int bid = blockIdx.x;
    if (bid < 512) {
        __shared__ float basis[KB];
        __shared__ float bred[32];
        if (tid < KB) {
            const float s   = x[(size_t)(BATCH - 1) * XDIM + 1];
            const float arg = s * dil[0] + shf[0];
            const float n   = 16.0f * (float)(tid & 15) / 15.0f;
            const float a   = arg * n;
            basis[tid] = (tid < 16) ? cosf(a) : sinf(a);
        }
        __syncthreads();
        const int m  = bid >> 2, kq = bid & 3;
        const int k8 = kq * 128 + tid;
        const int k  = k8 * 8;
        float acc[8] = {0.f,0.f,0.f,0.f,0.f,0.f,0.f,0.f};
        const float* src = fc2_w + (size_t)m * KB * KDIM + k;
        #pragma unroll 4
        for (int kb = 0; kb < KB; ++kb) {
            const float wgt = basis[kb];
            const float4 a = *(const float4*)(src + (size_t)kb * KDIM);
            const float4 b = *(const float4*)(src + (size_t)kb * KDIM + 4);
            acc[0] = fmaf(wgt, a.x, acc[0]); acc[1] = fmaf(wgt, a.y, acc[1]);
            acc[2] = fmaf(wgt, a.z, acc[2]); acc[3] = fmaf(wgt, a.w, acc[3]);
            acc[4] = fmaf(wgt, b.x, acc[4]); acc[5] = fmaf(wgt, b.y, acc[5]);
            acc[6] = fmaf(wgt, b.z, acc[6]); acc[7] = fmaf(wgt, b.w, acc[7]);
        }
        const int ct = m >> 5, coln = m & 31;
        const int kc = k8 >> 1, kg = k8 & 1;
        const int lane = kg * 32 + coln;
        unsigned short t[8];
        #pragma unroll
        for (int i = 0; i < 8; ++i) t[i] = f2bf(acc[i]);
        *(uint4*)(wfrag + ((size_t)(kc * 4 + ct) * 64 + lane) * 8) = *(const uint4*)t;
        if (kq == 0 && tid < 32) bred[tid] = basis[tid] * fc2_b[m * KB + tid];
        __syncthreads();
        if (kq == 0 && tid == 0) {
            float s = 0.f;
            #pragma unroll
            for (int i = 0; i < 32; ++i) s += bred[i];
            beff[m] = s;
        }
    } else if (bid < 576) {
        const int slot = (bid - 512) * 128 + tid;
        const int lane = slot & 63;
        const int jt   = slot >> 6;
        const int j    = jt * 32 + swap23(lane & 31);
        const int kg   = lane >> 5;
        const float* src = fc1_w + (size_t)j * LATENT + kg * 8;
        const float4 a = *(const float4*)(src);
        const float4 b = *(const float4*)(src + 4);
        unsigned short t[8];
        t[0]=f2bf(a.x); t[1]=f2bf(a.y); t[2]=f2bf(a.z); t[3]=f2bf(a.w);
        t[4]=f2bf(b.x); t[5]=f2bf(b.y); t[6]=f2bf(b.z); t[7]=f2bf(b.w);
        *(uint4*)(f1frag + (size_t)slot * 8) = *(const uint4*)t;
    } else {
        const int jt = tid;
        #pragma unroll
        for (int mp = 0; mp < 32; ++mp) {
            const int lg = mp >> 4, r = mp & 15;
            const int crow = (r & 3) + 8 * (r >> 2) + 4 * lg;
            bh[jt * 32 + mp] = fc1_b[jt * 32 + swap23(crow)];
        }
    }
}

// ---------------------------------------------------------------------------
// Fused (T3/T4 counted-vmcnt LDS ring): 256 blocks x 1024 thr (16 waves).
// Wave = (ks = w>>2, wi = w&3; rt = wi&1, ctp = wi>>1). Per ks-group a shared
// 4-slot x 8KB LDS ring of B-frags, filled by global_load_lds (each wave DMAs
// frag pair {2wi, 2wi+1}; each frag consumed by 2 waves). Per iter t:
//   s_waitcnt vmcnt(4)  [counted: dma(t)+fv(t+1) retired, 4 loads in flight]
//   s_barrier           [slot t&3 certified block-wide]
//   ds_read_b128 x4 -> B; issue dma(t+2) + fv(t+4)
//   pack hc(t); hc <- hT(t+1)  [single-hc WAR, decoupled]; 4 mains
// Tail: full drain, ring realiased as wfull, 4-pass ks-reduce + epilogue.
// ---------------------------------------------------------------------------
__global__ __launch_bounds__(1024, 4) void fused_kernel(
    const float* __restrict__ x,
    const unsigned short* __restrict__ wfrag,
    const unsigned short* __restrict__ f1frag,
    const float* __restrict__ bh,
    const float* __restrict__ beff, float* __restrict__ out)
{
    extern __shared__ char smem[];
    unsigned short* ring = (unsigned short*)smem;        // 128 KB
    float* bhs   = (float*)(smem + 131072);              // 132*32 f32 (pad zeroed)
    float* wfull = (float*)smem;                         // epilogue alias

    const int tid = threadIdx.x;
    const int w   = tid >> 6, l = tid & 63;
    const int l31 = l & 31,  lg = l >> 5;
    const int row0 = blockIdx.x * BM;
    const int ks = w >> 2, wi = w & 3;
    const int rt = wi & 1, ctp = wi >> 1;
    const int jt0 = ks * 32;

    // stage bias table + zero the overrun pad rows (128..131)
    ((float4*)bhs)[tid] = ((const float4*)bh)[tid];
    if (tid < 32) ((float4*)bhs)[1024 + tid] = make_float4(0.f, 0.f, 0.f, 0.f);

    // zfrag: lane l holds z[row0 + rt*32 + l31][lg*8 + r]  (loop-invariant)
    s16x8 zfrag;
    {
        const float* zp = x + (size_t)(row0 + rt * 32 + l31) * XDIM + 2 + lg * 8;
        #pragma unroll
        for (int q = 0; q < 4; ++q) {
            const float2 t = *(const float2*)(zp + 2 * q);
            ((unsigned*)&zfrag)[q] = pack_bf2(t.x, t.y);
        }
    }

    f32x16 acc0, acc1;
    #pragma unroll
    for (int i = 0; i < 16; ++i) { acc0[i] = 0.0f; acc1[i] = 0.0f; }

    // DMA: stage j-tile (jt0+t) frag pair {2wi, 2wi+1} into slot t&3
    auto dma = [&](int t) {
        const int jt = jt0 + t;
        const unsigned short* s0 = wfrag + ((size_t)(2 * jt) * 4 + wi) * 512 + l * 8;
        unsigned short* d = ring + ((size_t)(ks * 4 + (t & 3)) * 8 + 2 * wi) * 512;
        __builtin_amdgcn_global_load_lds(
            (const __attribute__((address_space(1))) unsigned*)s0,
            (__attribute__((address_space(3))) unsigned*)d, 16, 0, 0);
        __builtin_amdgcn_global_load_lds(
            (const __attribute__((address_space(1))) unsigned*)(s0 + 4 * 512),
            (__attribute__((address_space(3))) unsigned*)(d + 512), 16, 0, 0);
    };
    auto fvld = [&](int t) -> uint4 {
        return *(const uint4*)(f1frag + ((size_t)(jt0 + t) * 64 + l) * 8);
    };
    auto hinit = [&](int t) -> f32x16 {
        const float* bq = bhs + (jt0 + t) * 32 + lg * 16;
        const float4 c0 = *(const float4*)(bq);
        const float4 c1 = *(const float4*)(bq + 4);
        const float4 c2 = *(const float4*)(bq + 8);
        const float4 c3 = *(const float4*)(bq + 12);
        f32x16 hc;
        hc[0]=c0.x;  hc[1]=c0.y;  hc[2]=c0.z;  hc[3]=c0.w;
        hc[4]=c1.x;  hc[5]=c1.y;  hc[6]=c1.z;  hc[7]=c1.w;
        hc[8]=c2.x;  hc[9]=c2.y;  hc[10]=c2.z; hc[11]=c2.w;
        hc[12]=c3.x; hc[13]=c3.y; hc[14]=c3.z; hc[15]=c3.w;
        return hc;
    };

    // prologue: bhs visible; hc(0); FIFO = [fv0, dma(0)x2, F1, dma(1)x2, F2, F3]
    __syncthreads();
    const uint4 fv0 = fvld(0);
    f32x16 hc = __builtin_amdgcn_mfma_f32_32x32x16_bf16(
        *(const s16x8*)&fv0, zfrag, hinit(0), 0, 0, 0);
    dma(0);
    uint4 F1 = fvld(1);
    dma(1);
    uint4 F2 = fvld(2);
    uint4 F3 = fvld(3);
    uint4 F0;   // filled by body(t%4==0) with fv(t+4)

    // body: consume slot t&3 and hc(t); produce hc(t+1); issue dma(t+2), fv(t+4)
    auto body = [&](int t, uint4& F_use, uint4& F_fill) {
        asm volatile("s_waitcnt vmcnt(4)" ::: "memory");
        __builtin_amdgcn_s_barrier();
        __builtin_amdgcn_sched_barrier(0);
        const unsigned short* sb = ring + ((size_t)(ks * 4 + (t & 3)) * 8 + 4 * ctp) * 512 + l * 8;
        const s16x8 Ba = *(const s16x8*)(sb);
        const s16x8 Bb = *(const s16x8*)(sb + 512);
        const s16x8 Bc = *(const s16x8*)(sb + 1024);
        const s16x8 Bd = *(const s16x8*)(sb + 1536);
        dma(t + 2);
        F_fill = fvld(t + 4);
        unsigned p0[4], p1[4];
        #pragma unroll
        for (int q = 0; q < 4; ++q) {
            p0[q] = pack_bf2(fmaxf(hc[2*q],   0.f), fmaxf(hc[2*q+1],   0.f));
            p1[q] = pack_bf2(fmaxf(hc[8+2*q], 0.f), fmaxf(hc[8+2*q+1], 0.f));
        }
        hc = __builtin_amdgcn_mfma_f32_32x32x16_bf16(*(const s16x8*)&F_use, zfrag,
                                                     hinit(t + 1), 0, 0, 0);
        acc0 = __builtin_amdgcn_mfma_f32_32x32x16_bf16(*(const s16x8*)p0, Ba, acc0, 0, 0, 0);
        acc0 = __builtin_amdgcn_mfma_f32_32x32x16_bf16(*(const s16x8*)p1, Bb, acc0, 0, 0, 0);
        acc1 = __builtin_amdgcn_mfma_f32_32x32x16_bf16(*(const s16x8*)p0, Bc, acc1, 0, 0, 0);
        acc1 = __builtin_amdgcn_mfma_f32_32x32x16_bf16(*(const s16x8*)p1, Bd, acc1, 0, 0, 0);
    };

    #pragma unroll 1
    for (int o = 0; o < 8; ++o) {
        const int t = o * 4;
        body(t + 0, F1, F0);
        body(t + 1, F2, F1);
        body(t + 2, F3, F2);
        body(t + 3, F0, F3);
    }

    // drain everything, then realias ring as wfull
    asm volatile("s_waitcnt vmcnt(0) lgkmcnt(0)" ::: "memory");
    __syncthreads();

    // deterministic sequential ks-reduce + b_eff (4 passes)
    #pragma unroll 1
    for (int p = 0; p < 4; ++p) {
        if (ks == p) {
            const float be0 = beff[(2 * ctp) * 32 + l31];
            const float be1 = beff[(2 * ctp + 1) * 32 + l31];
            #pragma unroll
            for (int r = 0; r < 16; ++r) {
                const int rowl = (r & 3) + 8 * (r >> 2) + 4 * lg;
                const int idx  = (rt * 32 + rowl) * NM + (2 * ctp) * 32 + l31;
                if (p == 0) {
                    wfull[idx]      = acc0[r] + be0;
                    wfull[idx + 32] = acc1[r] + be1;
                } else {
                    wfull[idx]      += acc0[r];
                    wfull[idx + 32] += acc1[r];
                }
            }
        }
        __syncthreads();
    }

    // out[b,o] = inp[b] * w[b,o] + w[b,64+o]
    {
        const int o = tid & 63, rg = tid >> 6;
        #pragma unroll
        for (int i = 0; i < 4; ++i) {
            const int r = rg * 4 + i;
            const float inp = x[(size_t)(row0 + r) * XDIM];
            out[(size_t)(row0 + r) * OUTF + o] =
                fmaf(inp, wfull[r * NM + o], wfull[r * NM + OUTF + o]);
        }
    }
}

// ---------------------------------------------------------------------------
extern "C" void kernel_launch(void* const* d_in, const int* in_sizes, int n_in,
                              void* d_out, int out_size, void* d_ws, size_t ws_size,
                              hipStream_t stream) {
    const float* x     = (const float*)d_in[0];
    const float* fc1_w = (const float*)d_in[1];
    const float* fc1_b = (const float*)d_in[2];
    const float* fc2_w = (const float*)d_in[3];
    const float* fc2_b = (const float*)d_in[4];
    const float* dil   = (const float*)d_in[5];
    const float* shf   = (const float*)d_in[6];
    float* out = (float*)d_out;

    // ws: wfrag 1 MB | f1frag 128 KB | beff 512 B | bh 16 KB
    unsigned short* wfrag  = (unsigned short*)d_ws;
    unsigned short* f1frag = wfrag + 524288;
    float*          beff   = (float*)(f1frag + 65536);
    float*          bh     = beff + NM;

    hipFuncSetAttribute((const void*)fused_kernel,
                        hipFuncAttributeMaxDynamicSharedMemorySize, LDS_BYTES);

    precompute_kernel<<<577, 128, 0, stream>>>(x, fc1_w, fc1_b, fc2_w, fc2_b,
                                               dil, shf, wfrag, f1frag, bh, beff);
    fused_kernel<<<BATCH / BM, 1024, LDS_BYTES, stream>>>(x, wfrag, f1frag, bh,
                                                          beff, out);
}

// Round 13
// 46.021 us; speedup vs baseline: 2.2504x; 1.0673x over previous
//
#include <hip/hip_runtime.h>
#include <hip/hip_bf16.h>
#include <math.h>

#define BATCH  16384
#define XDIM   18
#define LATENT 16
#define NM     128
#define KDIM   4096
#define OUTF   64
#define KB     32
#define BM     64

#define LDS_BYTES 147968   // bhs 16896 B + part 131072 B

typedef short s16x8 __attribute__((ext_vector_type(8)));
typedef float f32x16 __attribute__((ext_vector_type(16)));

__device__ __forceinline__ unsigned short f2bf(float f) {
    union { float f; unsigned u; } v; v.f = f;
    return (unsigned short)((v.u + 0x7FFFu + ((v.u >> 16) & 1u)) >> 16);
}
__device__ __forceinline__ unsigned pack_bf2(float a, float b) {
    __hip_bfloat162 h = __float22bfloat162_rn(make_float2(a, b));  // v_cvt_pk_bf16_f32
    return *(unsigned*)&h;
}
// swap bits 2 and 3 (the sigma' map: hacc C-row -> k index) — HW-verified r4-r12
__device__ __forceinline__ int swap23(int m) {
    return (m & ~12) | ((m & 4) << 1) | ((m & 8) >> 1);
}

// ---------------------------------------------------------------------------
// Precompute (unchanged, proven r4-r12): W_eff -> wfrag (B-frag layout),
// fc1_w -> f1frag (A-frag layout, sigma-permuted cols), fc1_b -> bh
// (hacc/C-layout, sigma-permuted), b_eff.
// wfrag:  [kc 0..255][ct 0..3][lane 0..63][8 bf16]
// f1frag: [jt 0..127][lane 0..63][8 bf16]
// ---------------------------------------------------------------------------
__global__ __launch_bounds__(128) void precompute_kernel(
    const float* __restrict__ x, const float* __restrict__ fc1_w,
    const float* __restrict__ fc1_b, const float* __restrict__ fc2_w,
    const float* __restrict__ fc2_b, const float* __restrict__ dil,
    const float* __restrict__ shf, unsigned short* __restrict__ wfrag,
    unsigned short* __restrict__ f1frag, float* __restrict__ bh,
    float* __restrict__ beff)
{
    const int tid = threadIdx.x;
    const int bid = blockIdx.x;
    if (bid < 512) {
        __shared__ float basis[KB];
        __shared__ float bred[32];
        if (tid < KB) {
            const float s   = x[(size_t)(BATCH - 1) * XDIM + 1];
            const float arg = s * dil[0] + shf[0];
            const float n   = 16.0f * (float)(tid & 15) / 15.0f;
            const float a   = arg * n;
            basis[tid] = (tid < 16) ? cosf(a) : sinf(a);
        }
        __syncthreads();
        const int m  = bid >> 2, kq = bid & 3;
        const int k8 = kq * 128 + tid;
        const int k  = k8 * 8;
        float acc[8] = {0.f,0.f,0.f,0.f,0.f,0.f,0.f,0.f};
        const float* src = fc2_w + (size_t)m * KB * KDIM + k;
        #pragma unroll 4
        for (int kb = 0; kb < KB; ++kb) {
            const float wgt = basis[kb];
            const float4 a = *(const float4*)(src + (size_t)kb * KDIM);
            const float4 b = *(const float4*)(src + (size_t)kb * KDIM + 4);
            acc[0] = fmaf(wgt, a.x, acc[0]); acc[1] = fmaf(wgt, a.y, acc[1]);
            acc[2] = fmaf(wgt, a.z, acc[2]); acc[3] = fmaf(wgt, a.w, acc[3]);
            acc[4] = fmaf(wgt, b.x, acc[4]); acc[5] = fmaf(wgt, b.y, acc[5]);
            acc[6] = fmaf(wgt, b.z, acc[6]); acc[7] = fmaf(wgt, b.w, acc[7]);
        }
        const int ct = m >> 5, coln = m & 31;
        const int kc = k8 >> 1, kg = k8 & 1;
        const int lane = kg * 32 + coln;
        unsigned short t[8];
        #pragma unroll
        for (int i = 0; i < 8; ++i) t[i] = f2bf(acc[i]);
        *(uint4*)(wfrag + ((size_t)(kc * 4 + ct) * 64 + lane) * 8) = *(const uint4*)t;
        if (kq == 0 && tid < 32) bred[tid] = basis[tid] * fc2_b[m * KB + tid];
        __syncthreads();
        if (kq == 0 && tid == 0) {
            float s = 0.f;
            #pragma unroll
            for (int i = 0; i < 32; ++i) s += bred[i];
            beff[m] = s;
        }
    } else if (bid < 576) {
        const int slot = (bid - 512) * 128 + tid;
        const int lane = slot & 63;
        const int jt   = slot >> 6;
        const int j    = jt * 32 + swap23(lane & 31);
        const int kg   = lane >> 5;
        const float* src = fc1_w + (size_t)j * LATENT + kg * 8;
        const float4 a = *(const float4*)(src);
        const float4 b = *(const float4*)(src + 4);
        unsigned short t[8];
        t[0]=f2bf(a.x); t[1]=f2bf(a.y); t[2]=f2bf(a.z); t[3]=f2bf(a.w);
        t[4]=f2bf(b.x); t[5]=f2bf(b.y); t[6]=f2bf(b.z); t[7]=f2bf(b.w);
        *(uint4*)(f1frag + (size_t)slot * 8) = *(const uint4*)t;
    } else {
        const int jt = tid;
        #pragma unroll
        for (int mp = 0; mp < 32; ++mp) {
            const int lg = mp >> 4, r = mp & 15;
            const int crow = (r & 3) + 8 * (r >> 2) + 4 * lg;
            bh[jt * 32 + mp] = fc1_b[jt * 32 + swap23(crow)];
        }
    }
}

// ---------------------------------------------------------------------------
// Fused (r9 structure + setprio + single-pass parallel tail):
// 256 blocks x 1024 thr (16 waves, 1 blk/CU). Wave = (rt = w&1,
// ctp = (w>>1)&1, ks = w>>2): rows rt*32..+32, cols ctp*64..+64, j-tiles
// ks*32..+32. Per body t: pack hc(t) (computed previous iter), setprio(1),
// 4 main MFMAs, setprio(0), hc <- hT(t+1), prefetch B(t+2)/fv(t+3).
// Tail: each wave writes its 32x64 partial to a PRIVATE 8KB LDS region
// (no races), one barrier, epilogue sums the 4 ks-partials per output.
// ---------------------------------------------------------------------------
__global__ __launch_bounds__(1024, 4) void fused_kernel(
    const float* __restrict__ x,
    const unsigned short* __restrict__ wfrag,
    const unsigned short* __restrict__ f1frag,
    const float* __restrict__ bh,
    const float* __restrict__ beff, float* __restrict__ out)
{
    extern __shared__ char smem[];
    float* bhs  = (float*)smem;              // 132*32 f32 (pad rows zeroed)
    float* part = (float*)(smem + 16896);    // 16 waves x 2048 f32 partials

    const int tid = threadIdx.x;
    const int w   = tid >> 6, l = tid & 63;
    const int l31 = l & 31,  lg = l >> 5;
    const int row0 = blockIdx.x * BM;
    const int rt = w & 1, ctp = (w >> 1) & 1, ks = w >> 2;

    // stage bias table + zero the 4-row overrun pad
    ((float4*)bhs)[tid] = ((const float4*)bh)[tid];
    if (tid < 32) ((float4*)bhs)[1024 + tid] = make_float4(0.f, 0.f, 0.f, 0.f);

    // zfrag: lane l holds z[row0 + rt*32 + l31][lg*8 + r]  (loop-invariant)
    s16x8 zfrag;
    {
        const float* zp = x + (size_t)(row0 + rt * 32 + l31) * XDIM + 2 + lg * 8;
        #pragma unroll
        for (int q = 0; q < 4; ++q) {
            const float2 t = *(const float2*)(zp + 2 * q);
            ((unsigned*)&zfrag)[q] = pack_bf2(t.x, t.y);
        }
    }

    f32x16 acc0, acc1;
    #pragma unroll
    for (int i = 0; i < 16; ++i) { acc0[i] = 0.0f; acc1[i] = 0.0f; }

    // pointers: fv(i) at fvp + i*512; B(i) at bp + i*4096 (kc1 at +2048)
    const unsigned short* fvp = f1frag + ((size_t)(ks * 32) * 64 + l) * 8;
    const unsigned short* bp  = wfrag + ((size_t)(2 * (ks * 32)) * 4 + 2 * ctp) * 512 + l * 8;

    // prologue global loads
    const uint4 fv0 = *(const uint4*)(fvp);
    uint4 fvA = *(const uint4*)(fvp + 512);    // fv(t+1) for even bodies
    uint4 fvB = *(const uint4*)(fvp + 1024);   // fv(t+2) for odd bodies
    s16x8 B0E = *(const s16x8*)(bp);
    s16x8 B1E = *(const s16x8*)(bp + 512);
    s16x8 B2E = *(const s16x8*)(bp + 2048);
    s16x8 B3E = *(const s16x8*)(bp + 2560);
    s16x8 B0O = *(const s16x8*)(bp + 4096);
    s16x8 B1O = *(const s16x8*)(bp + 4096 + 512);
    s16x8 B2O = *(const s16x8*)(bp + 4096 + 2048);
    s16x8 B3O = *(const s16x8*)(bp + 4096 + 2560);

    __syncthreads();   // bhs ready
    const float* bhp = bhs + (ks * 32) * 32 + lg * 16;

    auto hinit = [&](const float* bq) -> f32x16 {
        const float4 c0 = *(const float4*)(bq);
        const float4 c1 = *(const float4*)(bq + 4);
        const float4 c2 = *(const float4*)(bq + 8);
        const float4 c3 = *(const float4*)(bq + 12);
        f32x16 hc;
        hc[0]=c0.x;  hc[1]=c0.y;  hc[2]=c0.z;  hc[3]=c0.w;
        hc[4]=c1.x;  hc[5]=c1.y;  hc[6]=c1.z;  hc[7]=c1.w;
        hc[8]=c2.x;  hc[9]=c2.y;  hc[10]=c2.z; hc[11]=c2.w;
        hc[12]=c3.x; hc[13]=c3.y; hc[14]=c3.z; hc[15]=c3.w;
        return hc;
    };

    // hc(0) ready before the loop
    f32x16 hcA = __builtin_amdgcn_mfma_f32_32x32x16_bf16(
        *(const s16x8*)&fv0, zfrag, hinit(bhp), 0, 0, 0);
    f32x16 hcB;

    for (int t = 0; t < 32; t += 2) {
        // ---- even iter t: pack hc(t), 4 mains (setprio), issue hT(t+1) ----
        {
            unsigned p0[4], p1[4];
            #pragma unroll
            for (int q = 0; q < 4; ++q) {
                p0[q] = pack_bf2(fmaxf(hcA[2*q],   0.f), fmaxf(hcA[2*q+1],   0.f));
                p1[q] = pack_bf2(fmaxf(hcA[8+2*q], 0.f), fmaxf(hcA[8+2*q+1], 0.f));
            }
            __builtin_amdgcn_s_setprio(1);
            acc0 = __builtin_amdgcn_mfma_f32_32x32x16_bf16(*(const s16x8*)p0, B0E, acc0, 0, 0, 0);
            acc1 = __builtin_amdgcn_mfma_f32_32x32x16_bf16(*(const s16x8*)p0, B1E, acc1, 0, 0, 0);
            acc0 = __builtin_amdgcn_mfma_f32_32x32x16_bf16(*(const s16x8*)p1, B2E, acc0, 0, 0, 0);
            acc1 = __builtin_amdgcn_mfma_f32_32x32x16_bf16(*(const s16x8*)p1, B3E, acc1, 0, 0, 0);
            __builtin_amdgcn_s_setprio(0);
        }
        hcB = __builtin_amdgcn_mfma_f32_32x32x16_bf16(
            *(const s16x8*)&fvA, zfrag, hinit(bhp + 32), 0, 0, 0);   // hc(t+1)
        fvA = *(const uint4*)(fvp + 1536);            // fv(t+3)
        B0E = *(const s16x8*)(bp + 8192);             // B(t+2)
        B1E = *(const s16x8*)(bp + 8192 + 512);
        B2E = *(const s16x8*)(bp + 8192 + 2048);
        B3E = *(const s16x8*)(bp + 8192 + 2560);

        // ---- odd iter t+1: pack hc(t+1), 4 mains (setprio), issue hT(t+2) ----
        {
            unsigned p0[4], p1[4];
            #pragma unroll
            for (int q = 0; q < 4; ++q) {
                p0[q] = pack_bf2(fmaxf(hcB[2*q],   0.f), fmaxf(hcB[2*q+1],   0.f));
                p1[q] = pack_bf2(fmaxf(hcB[8+2*q], 0.f), fmaxf(hcB[8+2*q+1], 0.f));
            }
            __builtin_amdgcn_s_setprio(1);
            acc0 = __builtin_amdgcn_mfma_f32_32x32x16_bf16(*(const s16x8*)p0, B0O, acc0, 0, 0, 0);
            acc1 = __builtin_amdgcn_mfma_f32_32x32x16_bf16(*(const s16x8*)p0, B1O, acc1, 0, 0, 0);
            acc0 = __builtin_amdgcn_mfma_f32_32x32x16_bf16(*(const s16x8*)p1, B2O, acc0, 0, 0, 0);
            acc1 = __builtin_amdgcn_mfma_f32_32x32x16_bf16(*(const s16x8*)p1, B3O, acc1, 0, 0, 0);
            __builtin_amdgcn_s_setprio(0);
        }
        hcA = __builtin_amdgcn_mfma_f32_32x32x16_bf16(
            *(const s16x8*)&fvB, zfrag, hinit(bhp + 64), 0, 0, 0);   // hc(t+2)
        fvB = *(const uint4*)(fvp + 2048);            // fv(t+4)
        B0O = *(const s16x8*)(bp + 12288);            // B(t+3)
        B1O = *(const s16x8*)(bp + 12288 + 512);
        B2O = *(const s16x8*)(bp + 12288 + 2048);
        B3O = *(const s16x8*)(bp + 12288 + 2560);

        fvp += 1024; bp += 8192; bhp += 64;
    }

    // ---- tail: parallel partial dump (private region per wave), 1 barrier ----
    {
        float* mypart = part + w * 2048;   // [32 rows][64 cols] local tile
        #pragma unroll
        for (int r = 0; r < 16; ++r) {
            const int rowl = (r & 3) + 8 * (r >> 2) + 4 * lg;
            mypart[rowl * 64 + l31]      = acc0[r];   // local cols 0..31
            mypart[rowl * 64 + 32 + l31] = acc1[r];   // local cols 32..63
        }
    }
    __syncthreads();

    // epilogue: out[b,o] = inp[b] * w[b,o] + w[b,64+o];
    // w[b,c] = beff[c] + sum_ks part[(rt + 2*ctp(c) + 4*ks)][rl*64 + (c&63)]
    {
        const int o = tid & 63, rg = tid >> 6;
        const float belo = beff[o], behi = beff[o + 64];
        #pragma unroll
        for (int i = 0; i < 4; ++i) {
            const int r   = rg * 4 + i;
            const int rt_ = r >> 5, rl = r & 31;
            float wlo = belo, whi = behi;
            #pragma unroll
            for (int ksi = 0; ksi < 4; ++ksi) {
                wlo += part[(rt_ + 4 * ksi) * 2048 + rl * 64 + o];       // ctp=0
                whi += part[(rt_ + 2 + 4 * ksi) * 2048 + rl * 64 + o];   // ctp=1
            }
            const float inp = x[(size_t)(row0 + r) * XDIM];
            out[(size_t)(row0 + r) * OUTF + o] = fmaf(inp, wlo, whi);
        }
    }
}

// ---------------------------------------------------------------------------
extern "C" void kernel_launch(void* const* d_in, const int* in_sizes, int n_in,
                              void* d_out, int out_size, void* d_ws, size_t ws_size,
                              hipStream_t stream) {
    const float* x     = (const float*)d_in[0];
    const float* fc1_w = (const float*)d_in[1];
    const float* fc1_b = (const float*)d_in[2];
    const float* fc2_w = (const float*)d_in[3];
    const float* fc2_b = (const float*)d_in[4];
    const float* dil   = (const float*)d_in[5];
    const float* shf   = (const float*)d_in[6];
    float* out = (float*)d_out;

    // ws: wfrag 1 MB | f1frag 128 KB | beff 512 B | bh 16 KB
    unsigned short* wfrag  = (unsigned short*)d_ws;
    unsigned short* f1frag = wfrag + 524288;
    float*          beff   = (float*)(f1frag + 65536);
    float*          bh     = beff + NM;

    hipFuncSetAttribute((const void*)fused_kernel,
                        hipFuncAttributeMaxDynamicSharedMemorySize, LDS_BYTES);

    precompute_kernel<<<577, 128, 0, stream>>>(x, fc1_w, fc1_b, fc2_w, fc2_b,
                                               dil, shf, wfrag, f1frag, bh, beff);
    fused_kernel<<<BATCH / BM, 1024, LDS_BYTES, stream>>>(x, wfrag, f1frag, bh,
                                                          beff, out);
}